// Round 3
// baseline (304.192 us; speedup 1.0000x reference)
//
#include <hip/hip_runtime.h>
#include <hip/hip_bf16.h>

#define SL 2048
#define NH 16
#define HD 128
#define EMB 2048

typedef __attribute__((ext_vector_type(8))) __bf16 bf16x8;
typedef __attribute__((ext_vector_type(4))) float f32x4;
typedef __attribute__((ext_vector_type(8))) short short8;

__device__ __forceinline__ short bf16bits(float x) {
  union { __hip_bfloat16 h; short s; } u;
  u.h = __float2bfloat16(x);
  return u.s;
}

#define GLDS16(gp, lp) __builtin_amdgcn_global_load_lds( \
    (__attribute__((address_space(1))) void*)(gp), \
    (__attribute__((address_space(3))) void*)(lp), 16, 0, 0)

// ---------------------------------------------------------------- casts
__global__ __launch_bounds__(256) void cast_f32_bf16(const float* __restrict__ in,
                                                     short* __restrict__ out, int n) {
  int i = (blockIdx.x * 256 + threadIdx.x) * 8;
  if (i >= n) return;
  float4 a = *(const float4*)(in + i);
  float4 b = *(const float4*)(in + i + 4);
  short8 o;
  o[0] = bf16bits(a.x); o[1] = bf16bits(a.y); o[2] = bf16bits(a.z); o[3] = bf16bits(a.w);
  o[4] = bf16bits(b.x); o[5] = bf16bits(b.y); o[6] = bf16bits(b.z); o[7] = bf16bits(b.w);
  *(short8*)(out + i) = o;
}

// --------------------------------------------- 2-phase dbuf NT GEMM, 128x128 tile
// C[m,n] = sum_k A[m,k]*B[n,k].
// MODE 0: plain f32 C store (ld 2048).
// MODE 1: QKV. tn<16: fused rmsnorm+double-rope -> Qb,Kb bf16 [h][s][d] (h=tn).
//               tn==16: V^T bf16 [d][s] (ld 2048).
template<int MODE>
__global__ __launch_bounds__(256) void gemm_fused(const short* __restrict__ A,
                                                  const short* __restrict__ B,
                                                  float* __restrict__ C,
                                                  short* __restrict__ Qb,
                                                  short* __restrict__ Kb,
                                                  short* __restrict__ VT,
                                                  const float* __restrict__ cosT,
                                                  const float* __restrict__ sinT,
                                                  const float* __restrict__ gamma) {
  __shared__ short smem[2][2][128 * 32];   // [buf][A/B][row][k] 32 KB
  const int K = 2048;
  int tn = blockIdx.x, tm = blockIdx.y;
  int tid = threadIdx.x;
  int wave = tid >> 6, lane = tid & 63;
  int g = lane >> 4, c = lane & 15;
  int wr = wave >> 1, wc = wave & 1;
  const short* Ab = A + (long)(tm * 128) * K;
  const short* Bb = B + (long)(tn * 128) * K;
  f32x4 zero = {0.f, 0.f, 0.f, 0.f};
  f32x4 acc[4][4];
#pragma unroll
  for (int m = 0; m < 4; ++m)
#pragma unroll
    for (int n = 0; n < 4; ++n) acc[m][n] = zero;

#define STAGE(buf, kt) do { \
    short* As_ = &smem[buf][0][0]; short* Bs_ = &smem[buf][1][0]; \
    _Pragma("unroll") \
    for (int hh = 0; hh < 2; ++hh) { \
      int rb = wave * 16 + hh * 64; \
      GLDS16(Ab + (long)(rb + (lane >> 2)) * K + (kt) + (lane & 3) * 8, As_ + rb * 32); \
      GLDS16(Bb + (long)(rb + (lane >> 2)) * K + (kt) + (lane & 3) * 8, Bs_ + rb * 32); \
    } } while (0)

  STAGE(0, 0);
  asm volatile("s_waitcnt vmcnt(0)" ::: "memory");
  __builtin_amdgcn_s_barrier();

  for (int it = 0; it < 64; ++it) {
    int cur = it & 1;
    if (it < 63) STAGE(cur ^ 1, (it + 1) * 32);
    const short* As = &smem[cur][0][0];
    const short* Bs = &smem[cur][1][0];
    bf16x8 a[4], b[4];
#pragma unroll
    for (int m = 0; m < 4; ++m) a[m] = *(const bf16x8*)(As + (wr * 64 + m * 16 + c) * 32 + g * 8);
#pragma unroll
    for (int n = 0; n < 4; ++n) b[n] = *(const bf16x8*)(Bs + (wc * 64 + n * 16 + c) * 32 + g * 8);
#pragma unroll
    for (int m = 0; m < 4; ++m)
#pragma unroll
      for (int n = 0; n < 4; ++n)
        acc[m][n] = __builtin_amdgcn_mfma_f32_16x16x32_bf16(a[m], b[n], acc[m][n], 0, 0, 0);
    if (it < 63) asm volatile("s_waitcnt vmcnt(0)" ::: "memory");
    __builtin_amdgcn_s_barrier();
  }
#undef STAGE

  if constexpr (MODE == 0) {
#pragma unroll
    for (int m = 0; m < 4; ++m)
#pragma unroll
      for (int n = 0; n < 4; ++n)
#pragma unroll
        for (int r = 0; r < 4; ++r) {
          int row = tm * 128 + wr * 64 + m * 16 + g * 4 + r;
          int col = tn * 128 + wc * 64 + n * 16 + c;
          C[(long)row * 2048 + col] = acc[m][n][r];
        }
  } else {
    if (tn < 16) {
      // fused rmsnorm + rope(Q) + rope(rope(Q)) epilogue
      __shared__ float ssb[2][128];
      __shared__ float xch[256 * 17];
      float ssmr[4][4];
#pragma unroll
      for (int m = 0; m < 4; ++m)
#pragma unroll
        for (int r = 0; r < 4; ++r) {
          float s = 0.f;
#pragma unroll
          for (int n = 0; n < 4; ++n) s += acc[m][n][r] * acc[m][n][r];
#pragma unroll
          for (int off = 1; off <= 8; off <<= 1) s += __shfl_xor(s, off, 64);
          ssmr[m][r] = s;   // sum over this wave's 64 cols, all c-lanes hold it
        }
      if (c == 0) {
#pragma unroll
        for (int m = 0; m < 4; ++m)
#pragma unroll
          for (int r = 0; r < 4; ++r)
            ssb[wc][wr * 64 + m * 16 + g * 4 + r] = ssmr[m][r];
      }
      __syncthreads();
      float rn[4][4];
#pragma unroll
      for (int m = 0; m < 4; ++m)
#pragma unroll
        for (int r = 0; r < 4; ++r) {
          int rowloc = wr * 64 + m * 16 + g * 4 + r;
          rn[m][r] = rsqrtf((ssb[0][rowloc] + ssb[1][rowloc]) * (1.0f / 128.0f) + 1e-6f);
        }
      float g_own[4], g_par[4];
#pragma unroll
      for (int n = 0; n < 4; ++n) {
        g_own[n] = gamma[wc * 64 + n * 16 + c];
        g_par[n] = gamma[(wc ^ 1) * 64 + n * 16 + c];
      }
      float sgn = wc ? 1.f : -1.f;
#pragma unroll
      for (int m = 0; m < 4; ++m) {
#pragma unroll
        for (int n = 0; n < 4; ++n)
#pragma unroll
          for (int r = 0; r < 4; ++r)
            xch[tid * 17 + n * 4 + r] = acc[m][n][r];
        __syncthreads();
        float xp[4][4];
#pragma unroll
        for (int n = 0; n < 4; ++n)
#pragma unroll
          for (int r = 0; r < 4; ++r)
            xp[n][r] = xch[(tid ^ 64) * 17 + n * 4 + r];
        __syncthreads();
#pragma unroll
        for (int n = 0; n < 4; ++n)
#pragma unroll
          for (int r = 0; r < 4; ++r) {
            int s = tm * 128 + wr * 64 + m * 16 + g * 4 + r;
            int u = n * 16 + c;                    // d mod 64 (cos/sin periodic in 64)
            float cv = cosT[s * 128 + u];
            float sv = sinT[s * 128 + u];
            float xo = acc[m][n][r] * rn[m][r] * g_own[n];
            float xq = xp[n][r] * rn[m][r] * g_par[n];
            float y  = xo * cv + sgn * xq * sv;    // rope(Q)
            float yp = xq * cv - sgn * xo * sv;    // rope(Q) at partner d
            float kk = y * cv + sgn * yp * sv;     // rope(rope(Q))  (reference bug)
            long o = ((long)tn * SL + s) * HD + wc * 64 + u;
            Qb[o] = bf16bits(y);
            Kb[o] = bf16bits(kk);
          }
      }
    } else {
      // V^T [d][s]
#pragma unroll
      for (int m = 0; m < 4; ++m)
#pragma unroll
        for (int n = 0; n < 4; ++n)
#pragma unroll
          for (int r = 0; r < 4; ++r) {
            int s = tm * 128 + wr * 64 + m * 16 + g * 4 + r;
            int d = wc * 64 + n * 16 + c;
            VT[(long)d * SL + s] = bf16bits(acc[m][n][r]);
          }
    }
  }
}

// ---------------------------------------------------------- causal flash attention
// Wave-independent: 512 blocks x 4 waves; each wave owns one (head, 16-row strip).
// No barriers. K direct global->reg; V via pre-transposed global VT; per-wave Ps LDS.
__global__ __launch_bounds__(256) void attn(const short* __restrict__ Qb,
                                            const short* __restrict__ Kb,
                                            const short* __restrict__ VT,
                                            short* __restrict__ att) {
  __shared__ short Ps[4][16 * 72];
  int wave = threadIdx.x >> 6, lane = threadIdx.x & 63;
  int g = lane >> 4, c = lane & 15;
  int b = blockIdx.x;
  // strip pairing: blocks b and b+256 get strips sb and 127-sb' with ntile sum ~33
  int sb = (b < 256) ? ((b >> 2) << 1) : (127 - (((b - 256) >> 2) << 1));
  int h  = ((b & 3) << 2) + wave;
  int qbase = sb << 4;
  int ntile = (sb >> 2) + 1;
  const short* Qh = Qb + (long)h * SL * HD;
  const short* Kh = Kb + (long)h * SL * HD;

  bf16x8 aq[4];
#pragma unroll
  for (int kc = 0; kc < 4; ++kc)
    aq[kc] = *(const bf16x8*)(Qh + (long)(qbase + c) * HD + kc * 32 + g * 8);

  float mrun[4], lrun[4];
#pragma unroll
  for (int r = 0; r < 4; ++r) { mrun[r] = -1e30f; lrun[r] = 0.f; }
  f32x4 zero = {0.f, 0.f, 0.f, 0.f};
  f32x4 O[8];
#pragma unroll
  for (int d8 = 0; d8 < 8; ++d8) O[d8] = zero;

  for (int kt = 0; kt < ntile; ++kt) {
    int kvb = kt * 64;
    // S = Q K^T   (K frags straight from global; 64B-chunk coalesced, L2-served)
    f32x4 sf[4];
#pragma unroll
    for (int n = 0; n < 4; ++n) sf[n] = zero;
#pragma unroll
    for (int kc = 0; kc < 4; ++kc)
#pragma unroll
      for (int n = 0; n < 4; ++n) {
        bf16x8 bk = *(const bf16x8*)(Kh + (long)(kvb + n * 16 + c) * HD + kc * 32 + g * 8);
        sf[n] = __builtin_amdgcn_mfma_f32_16x16x32_bf16(aq[kc], bk, sf[n], 0, 0, 0);
      }

    const float sc = 0.08838834764831845f;   // 1/sqrt(128)
    float tmax[4];
#pragma unroll
    for (int r = 0; r < 4; ++r) tmax[r] = -1e30f;
#pragma unroll
    for (int n = 0; n < 4; ++n)
#pragma unroll
      for (int r = 0; r < 4; ++r) {
        int q = qbase + g * 4 + r;
        int k = kvb + n * 16 + c;
        float v = sf[n][r] * sc;
        if (k > q) v = -1e30f;
        sf[n][r] = v;
        tmax[r] = fmaxf(tmax[r], v);
      }
#pragma unroll
    for (int r = 0; r < 4; ++r) {
      tmax[r] = fmaxf(tmax[r], __shfl_xor(tmax[r], 1, 64));
      tmax[r] = fmaxf(tmax[r], __shfl_xor(tmax[r], 2, 64));
      tmax[r] = fmaxf(tmax[r], __shfl_xor(tmax[r], 4, 64));
      tmax[r] = fmaxf(tmax[r], __shfl_xor(tmax[r], 8, 64));
    }
    float corr[4];
#pragma unroll
    for (int r = 0; r < 4; ++r) {
      float mn = fmaxf(mrun[r], tmax[r]);
      corr[r] = __expf(mrun[r] - mn);
      mrun[r] = mn;
      lrun[r] *= corr[r];
    }
#pragma unroll
    for (int d8 = 0; d8 < 8; ++d8)
#pragma unroll
      for (int r = 0; r < 4; ++r) O[d8][r] *= corr[r];
    float rs[4] = {0.f, 0.f, 0.f, 0.f};
#pragma unroll
    for (int n = 0; n < 4; ++n)
#pragma unroll
      for (int r = 0; r < 4; ++r) {
        float p = __expf(sf[n][r] - mrun[r]);
        rs[r] += p;
        Ps[wave][(g * 4 + r) * 72 + n * 16 + c] = bf16bits(p);
      }
#pragma unroll
    for (int r = 0; r < 4; ++r) {
      rs[r] += __shfl_xor(rs[r], 1, 64);
      rs[r] += __shfl_xor(rs[r], 2, 64);
      rs[r] += __shfl_xor(rs[r], 4, 64);
      rs[r] += __shfl_xor(rs[r], 8, 64);
      lrun[r] += rs[r];
    }
    // O += P V   (Ps same-wave LDS round trip; V^T rows direct from global)
#pragma unroll
    for (int k2 = 0; k2 < 2; ++k2) {
      bf16x8 ap = *(const bf16x8*)(&Ps[wave][c * 72 + k2 * 32 + g * 8]);
#pragma unroll
      for (int d8 = 0; d8 < 8; ++d8) {
        bf16x8 bv = *(const bf16x8*)(VT + (long)(d8 * 16 + c) * SL + kvb + k2 * 32 + g * 8);
        O[d8] = __builtin_amdgcn_mfma_f32_16x16x32_bf16(ap, bv, O[d8], 0, 0, 0);
      }
    }
  }
  // epilogue
#pragma unroll
  for (int d8 = 0; d8 < 8; ++d8)
#pragma unroll
    for (int r = 0; r < 4; ++r) {
      int q = qbase + g * 4 + r;
      float val = O[d8][r] / lrun[r];
      att[(long)q * EMB + h * HD + d8 * 16 + c] = bf16bits(val);
    }
}

// ---------------------------------------------------------------------- launch
extern "C" void kernel_launch(void* const* d_in, const int* in_sizes, int n_in,
                              void* d_out, int out_size, void* d_ws, size_t ws_size,
                              hipStream_t stream) {
  const float* x    = (const float*)d_in[0];
  const float* cosT = (const float*)d_in[1];
  const float* sinT = (const float*)d_in[2];
  const float* Wq   = (const float*)d_in[3];
  const float* Wv   = (const float*)d_in[5];
  const float* Wo   = (const float*)d_in[6];
  const float* qg   = (const float*)d_in[7];

  char* w = (char*)d_ws;
  short* xb   = (short*)(w + 0);          //  8.0 MB  x bf16 [2048][2048]
  short* wqvb = (short*)(w + 8388608);    //  8.5 MB  [Wq;Wv] bf16 [2176][2048]
  short* wob  = (short*)(w + 17301504);   //  8.0 MB  Wo bf16
  short* vt   = (short*)(w + 25690112);   //  0.5 MB  V^T bf16 [128][2048]
  short* qb   = (short*)(w + 26214400);   //  8.0 MB  Q roped bf16 [16][2048][128]
  short* kb   = (short*)(w + 34603008);   //  8.0 MB  K roped bf16 [16][2048][128]
  short* attb = (short*)(w + 42991616);   //  8.0 MB  att bf16 [2048][2048]

  cast_f32_bf16<<<dim3(2048), dim3(256), 0, stream>>>(x,  xb,   4194304);
  cast_f32_bf16<<<dim3(2048), dim3(256), 0, stream>>>(Wq, wqvb, 4194304);
  cast_f32_bf16<<<dim3(128),  dim3(256), 0, stream>>>(Wv, wqvb + 4194304, 262144);
  cast_f32_bf16<<<dim3(2048), dim3(256), 0, stream>>>(Wo, wob,  4194304);

  gemm_fused<1><<<dim3(17, 16), dim3(256), 0, stream>>>(xb, wqvb, nullptr, qb, kb, vt,
                                                        cosT, sinT, qg);
  attn<<<dim3(512), dim3(256), 0, stream>>>(qb, kb, vt, attb);
  gemm_fused<0><<<dim3(16, 16), dim3(256), 0, stream>>>(attb, wob, (float*)d_out,
                                                        nullptr, nullptr, nullptr,
                                                        nullptr, nullptr, nullptr);
}

// Round 6
// 200.010 us; speedup vs baseline: 1.5209x; 1.5209x over previous
//
#include <hip/hip_runtime.h>
#include <hip/hip_bf16.h>

#define SL 2048
#define NH 16
#define HD 128
#define EMB 2048

typedef __attribute__((ext_vector_type(8))) __bf16 bf16x8;
typedef __attribute__((ext_vector_type(4))) float f32x4;
typedef __attribute__((ext_vector_type(8))) short short8;

__device__ __forceinline__ short bf16bits(float x) {
  union { __hip_bfloat16 h; short s; } u;
  u.h = __float2bfloat16(x);
  return u.s;
}

#define GLDS16(gp, lp) __builtin_amdgcn_global_load_lds( \
    (__attribute__((address_space(1))) void*)(gp), \
    (__attribute__((address_space(3))) void*)(lp), 16, 0, 0)

// ---------------------------------------------------------------- casts
__global__ __launch_bounds__(256) void cast_f32_bf16(const float* __restrict__ in,
                                                     short* __restrict__ out, int n) {
  int i = (blockIdx.x * 256 + threadIdx.x) * 8;
  if (i >= n) return;
  float4 a = *(const float4*)(in + i);
  float4 b = *(const float4*)(in + i + 4);
  short8 o;
  o[0] = bf16bits(a.x); o[1] = bf16bits(a.y); o[2] = bf16bits(a.z); o[3] = bf16bits(a.w);
  o[4] = bf16bits(b.x); o[5] = bf16bits(b.y); o[6] = bf16bits(b.z); o[7] = bf16bits(b.w);
  *(short8*)(out + i) = o;
}

// --------------------------------------------- 2-phase dbuf NT GEMM, 128x128 tile
// (r2-proven code, verbatim)
// MODE 0: plain f32 C store (ld 2048).
// MODE 1: QKV. tn<16: fused rmsnorm+double-rope -> Qb,Kb bf16 [h][s][d] (h=tn).
//               tn==16: V^T bf16 [d][s] (ld 2048).
template<int MODE>
__global__ __launch_bounds__(256) void gemm_fused(const short* __restrict__ A,
                                                  const short* __restrict__ B,
                                                  float* __restrict__ C,
                                                  short* __restrict__ Qb,
                                                  short* __restrict__ Kb,
                                                  short* __restrict__ VT,
                                                  const float* __restrict__ cosT,
                                                  const float* __restrict__ sinT,
                                                  const float* __restrict__ gamma) {
  __shared__ short smem[2][2][128 * 32];   // [buf][A/B][row][k] 32 KB
  const int K = 2048;
  int tn = blockIdx.x, tm = blockIdx.y;
  int tid = threadIdx.x;
  int wave = tid >> 6, lane = tid & 63;
  int g = lane >> 4, c = lane & 15;
  int wr = wave >> 1, wc = wave & 1;
  const short* Ab = A + (long)(tm * 128) * K;
  const short* Bb = B + (long)(tn * 128) * K;
  f32x4 zero = {0.f, 0.f, 0.f, 0.f};
  f32x4 acc[4][4];
#pragma unroll
  for (int m = 0; m < 4; ++m)
#pragma unroll
    for (int n = 0; n < 4; ++n) acc[m][n] = zero;

#define STAGE(buf, kt) do { \
    short* As_ = &smem[buf][0][0]; short* Bs_ = &smem[buf][1][0]; \
    _Pragma("unroll") \
    for (int hh = 0; hh < 2; ++hh) { \
      int rb = wave * 16 + hh * 64; \
      GLDS16(Ab + (long)(rb + (lane >> 2)) * K + (kt) + (lane & 3) * 8, As_ + rb * 32); \
      GLDS16(Bb + (long)(rb + (lane >> 2)) * K + (kt) + (lane & 3) * 8, Bs_ + rb * 32); \
    } } while (0)

  STAGE(0, 0);
  asm volatile("s_waitcnt vmcnt(0)" ::: "memory");
  __builtin_amdgcn_s_barrier();

  for (int it = 0; it < 64; ++it) {
    int cur = it & 1;
    if (it < 63) STAGE(cur ^ 1, (it + 1) * 32);
    const short* As = &smem[cur][0][0];
    const short* Bs = &smem[cur][1][0];
    bf16x8 a[4], b[4];
#pragma unroll
    for (int m = 0; m < 4; ++m) a[m] = *(const bf16x8*)(As + (wr * 64 + m * 16 + c) * 32 + g * 8);
#pragma unroll
    for (int n = 0; n < 4; ++n) b[n] = *(const bf16x8*)(Bs + (wc * 64 + n * 16 + c) * 32 + g * 8);
#pragma unroll
    for (int m = 0; m < 4; ++m)
#pragma unroll
      for (int n = 0; n < 4; ++n)
        acc[m][n] = __builtin_amdgcn_mfma_f32_16x16x32_bf16(a[m], b[n], acc[m][n], 0, 0, 0);
    if (it < 63) asm volatile("s_waitcnt vmcnt(0)" ::: "memory");
    __builtin_amdgcn_s_barrier();
  }
#undef STAGE

  if constexpr (MODE == 0) {
#pragma unroll
    for (int m = 0; m < 4; ++m)
#pragma unroll
      for (int n = 0; n < 4; ++n)
#pragma unroll
        for (int r = 0; r < 4; ++r) {
          int row = tm * 128 + wr * 64 + m * 16 + g * 4 + r;
          int col = tn * 128 + wc * 64 + n * 16 + c;
          C[(long)row * 2048 + col] = acc[m][n][r];
        }
  } else {
    if (tn < 16) {
      // fused rmsnorm + rope(Q) + rope(rope(Q)) epilogue
      __shared__ float ssb[2][128];
      __shared__ float xch[256 * 17];
      float ssmr[4][4];
#pragma unroll
      for (int m = 0; m < 4; ++m)
#pragma unroll
        for (int r = 0; r < 4; ++r) {
          float s = 0.f;
#pragma unroll
          for (int n = 0; n < 4; ++n) s += acc[m][n][r] * acc[m][n][r];
#pragma unroll
          for (int off = 1; off <= 8; off <<= 1) s += __shfl_xor(s, off, 64);
          ssmr[m][r] = s;   // sum over this wave's 64 cols, all c-lanes hold it
        }
      if (c == 0) {
#pragma unroll
        for (int m = 0; m < 4; ++m)
#pragma unroll
          for (int r = 0; r < 4; ++r)
            ssb[wc][wr * 64 + m * 16 + g * 4 + r] = ssmr[m][r];
      }
      __syncthreads();
      float rn[4][4];
#pragma unroll
      for (int m = 0; m < 4; ++m)
#pragma unroll
        for (int r = 0; r < 4; ++r) {
          int rowloc = wr * 64 + m * 16 + g * 4 + r;
          rn[m][r] = rsqrtf((ssb[0][rowloc] + ssb[1][rowloc]) * (1.0f / 128.0f) + 1e-6f);
        }
      float g_own[4], g_par[4];
#pragma unroll
      for (int n = 0; n < 4; ++n) {
        g_own[n] = gamma[wc * 64 + n * 16 + c];
        g_par[n] = gamma[(wc ^ 1) * 64 + n * 16 + c];
      }
      float sgn = wc ? 1.f : -1.f;
#pragma unroll
      for (int m = 0; m < 4; ++m) {
#pragma unroll
        for (int n = 0; n < 4; ++n)
#pragma unroll
          for (int r = 0; r < 4; ++r)
            xch[tid * 17 + n * 4 + r] = acc[m][n][r];
        __syncthreads();
        float xp[4][4];
#pragma unroll
        for (int n = 0; n < 4; ++n)
#pragma unroll
          for (int r = 0; r < 4; ++r)
            xp[n][r] = xch[(tid ^ 64) * 17 + n * 4 + r];
        __syncthreads();
#pragma unroll
        for (int n = 0; n < 4; ++n)
#pragma unroll
          for (int r = 0; r < 4; ++r) {
            int s = tm * 128 + wr * 64 + m * 16 + g * 4 + r;
            int u = n * 16 + c;                    // d mod 64 (cos/sin periodic in 64)
            float cv = cosT[s * 128 + u];
            float sv = sinT[s * 128 + u];
            float xo = acc[m][n][r] * rn[m][r] * g_own[n];
            float xq = xp[n][r] * rn[m][r] * g_par[n];
            float y  = xo * cv + sgn * xq * sv;    // rope(Q)
            float yp = xq * cv - sgn * xo * sv;    // rope(Q) at partner d
            float kk = y * cv + sgn * yp * sv;     // rope(rope(Q))  (reference bug)
            long o = ((long)tn * SL + s) * HD + wc * 64 + u;
            Qb[o] = bf16bits(y);
            Kb[o] = bf16bits(kk);
          }
      }
    } else {
      // V^T [d][s]
#pragma unroll
      for (int m = 0; m < 4; ++m)
#pragma unroll
        for (int n = 0; n < 4; ++n)
#pragma unroll
          for (int r = 0; r < 4; ++r) {
            int s = tm * 128 + wr * 64 + m * 16 + g * 4 + r;
            int d = wc * 64 + n * 16 + c;
            VT[(long)d * SL + s] = bf16bits(acc[m][n][r]);
          }
    }
  }
}

// ---------------------------------------------------------- causal flash attention
// grid (32,16): 64 q rows/block, 4 waves x 16 rows; KV tiles 64; qt pairing.
// K tile: GLDS dbuf, source chunk-swizzle (c ^ (row&7)) -- proven since r1.
// V tile: V^T [128d][64k] staged by GLDS with the SAME swizzle pattern; B-frags are
// plain bf16x8 LDS reads (k-contiguous). ONE barrier/iter (all staging is GLDS, so
// per-wave vmcnt(0) before the barrier gives full visibility; WAR safe because all
// reads of a buffer are data-dep complete before the next top barrier).
// defer-max (T13, THR=8); row-sum reduce deferred to epilogue.
__global__ __launch_bounds__(256, 2) void attn(const short* __restrict__ Qb,
                                               const short* __restrict__ Kb,
                                               const short* __restrict__ VTg,
                                               short* __restrict__ att) {
  __shared__ short Ks[2][64 * 128];   // 32 KB
  __shared__ short Vs[2][128 * 64];   // 32 KB  V^T tile [d][k-chunk swizzled]
  __shared__ short Ps[4][16 * 72];    // 9 KB per-wave
  int wave = threadIdx.x >> 6, lane = threadIdx.x & 63;
  int g = lane >> 4, c = lane & 15;
  int h = blockIdx.y;
  int qt = (blockIdx.y & 8) ? (31 - blockIdx.x) : blockIdx.x;
  int qbase = qt * 64 + wave * 16;
  int ntile = qt + 1;
  const short* Qh = Qb + (long)h * SL * HD;
  const short* Kh = Kb + (long)h * SL * HD;

  bf16x8 aq[4];
#pragma unroll
  for (int kc = 0; kc < 4; ++kc)
    aq[kc] = *(const bf16x8*)(Qh + (long)(qbase + c) * HD + kc * 32 + g * 8);

  float mrun[4], lrun[4];
#pragma unroll
  for (int r = 0; r < 4; ++r) { mrun[r] = -1e30f; lrun[r] = 0.f; }
  f32x4 zero = {0.f, 0.f, 0.f, 0.f};
  f32x4 O[8];
#pragma unroll
  for (int d8 = 0; d8 < 8; ++d8) O[d8] = zero;

  // stage tile into buf b: K rows swizzled; V^T rows swizzled (identical pattern)
#define ASTAGE(b, kvb) do { \
    _Pragma("unroll") \
    for (int i = 0; i < 4; ++i) { \
      int rb = wave * 16 + i * 4; \
      int row = rb + (lane >> 4); \
      int c16 = (lane & 15) ^ (row & 7); \
      GLDS16(Kh + (long)((kvb) + row) * HD + c16 * 8, &Ks[b][rb * 128]); \
    } \
    _Pragma("unroll") \
    for (int i = 0; i < 4; ++i) { \
      int dbase = i * 32 + wave * 8; \
      int drow = dbase + (lane >> 3); \
      int u8 = (lane & 7) ^ (drow & 7); \
      GLDS16(VTg + (long)drow * SL + (kvb) + u8 * 8, &Vs[b][dbase * 64]); \
    } } while (0)

  ASTAGE(0, 0);

  for (int kt = 0; kt < ntile; ++kt) {
    int kvb = kt * 64;
    int bcu = kt & 1;
    asm volatile("s_waitcnt vmcnt(0)" ::: "memory");
    __builtin_amdgcn_s_barrier();
    if (kt + 1 < ntile) ASTAGE(bcu ^ 1, kvb + 64);

    // S = Q K^T
    f32x4 sf[4];
#pragma unroll
    for (int n = 0; n < 4; ++n) sf[n] = zero;
    __builtin_amdgcn_s_setprio(1);
#pragma unroll
    for (int kc = 0; kc < 4; ++kc)
#pragma unroll
      for (int n = 0; n < 4; ++n) {
        int row = n * 16 + c;
        int u = (kc * 4 + g) ^ (row & 7);
        bf16x8 bk = *(const bf16x8*)(&Ks[bcu][row * 128 + u * 8]);
        sf[n] = __builtin_amdgcn_mfma_f32_16x16x32_bf16(aq[kc], bk, sf[n], 0, 0, 0);
      }
    __builtin_amdgcn_s_setprio(0);

    const float sc = 0.08838834764831845f;   // 1/sqrt(128)
    float tmax[4];
#pragma unroll
    for (int r = 0; r < 4; ++r) tmax[r] = -1e30f;
#pragma unroll
    for (int n = 0; n < 4; ++n)
#pragma unroll
      for (int r = 0; r < 4; ++r) {
        int q = qbase + g * 4 + r;
        int k = kvb + n * 16 + c;
        float v = sf[n][r] * sc;
        if (k > q) v = -1e30f;
        sf[n][r] = v;
        tmax[r] = fmaxf(tmax[r], v);
      }
#pragma unroll
    for (int r = 0; r < 4; ++r) {
      tmax[r] = fmaxf(tmax[r], __shfl_xor(tmax[r], 1, 64));
      tmax[r] = fmaxf(tmax[r], __shfl_xor(tmax[r], 2, 64));
      tmax[r] = fmaxf(tmax[r], __shfl_xor(tmax[r], 4, 64));
      tmax[r] = fmaxf(tmax[r], __shfl_xor(tmax[r], 8, 64));
    }
    // defer-max (T13): rescale only if a row grew past THR=8
    int need = 0;
#pragma unroll
    for (int r = 0; r < 4; ++r) need |= (tmax[r] > mrun[r] + 8.f);
    if (__any(need)) {
#pragma unroll
      for (int r = 0; r < 4; ++r) {
        float mn = fmaxf(mrun[r], tmax[r]);
        float corr = __expf(mrun[r] - mn);
        mrun[r] = mn;
        lrun[r] *= corr;
#pragma unroll
        for (int d8 = 0; d8 < 8; ++d8) O[d8][r] *= corr;
      }
    }
    float rs[4] = {0.f, 0.f, 0.f, 0.f};
#pragma unroll
    for (int n = 0; n < 4; ++n)
#pragma unroll
      for (int r = 0; r < 4; ++r) {
        float p = __expf(sf[n][r] - mrun[r]);
        rs[r] += p;
        Ps[wave][(g * 4 + r) * 72 + n * 16 + c] = bf16bits(p);
      }
#pragma unroll
    for (int r = 0; r < 4; ++r) lrun[r] += rs[r];   // per-lane partial (no shfl)

    // O += P V : A-frags from Ps (q=c row, k contiguous); B-frags from Vs
    // (row d = d8*16+c, chunk (k2*4+g)^(c&7) undoes the source swizzle)
#pragma unroll
    for (int k2 = 0; k2 < 2; ++k2) {
      bf16x8 ap = *(const bf16x8*)(&Ps[wave][c * 72 + k2 * 32 + g * 8]);
      __builtin_amdgcn_s_setprio(1);
#pragma unroll
      for (int d8 = 0; d8 < 8; ++d8) {
        int drow = d8 * 16 + c;
        int u = (k2 * 4 + g) ^ (c & 7);
        bf16x8 bv = *(const bf16x8*)(&Vs[bcu][drow * 64 + u * 8]);
        O[d8] = __builtin_amdgcn_mfma_f32_16x16x32_bf16(ap, bv, O[d8], 0, 0, 0);
      }
      __builtin_amdgcn_s_setprio(0);
    }
  }
#undef ASTAGE

  // epilogue: reduce row sums (deferred), normalize, store
  float rsum[4];
#pragma unroll
  for (int r = 0; r < 4; ++r) {
    float s = lrun[r];
    s += __shfl_xor(s, 1, 64);
    s += __shfl_xor(s, 2, 64);
    s += __shfl_xor(s, 4, 64);
    s += __shfl_xor(s, 8, 64);
    rsum[r] = 1.0f / s;
  }
#pragma unroll
  for (int d8 = 0; d8 < 8; ++d8)
#pragma unroll
    for (int r = 0; r < 4; ++r) {
      int q = qbase + g * 4 + r;
      att[(long)q * EMB + h * HD + d8 * 16 + c] = bf16bits(O[d8][r] * rsum[r]);
    }
}

// ---------------------------------------------------------------------- launch
extern "C" void kernel_launch(void* const* d_in, const int* in_sizes, int n_in,
                              void* d_out, int out_size, void* d_ws, size_t ws_size,
                              hipStream_t stream) {
  const float* x    = (const float*)d_in[0];
  const float* cosT = (const float*)d_in[1];
  const float* sinT = (const float*)d_in[2];
  const float* Wq   = (const float*)d_in[3];
  const float* Wv   = (const float*)d_in[5];
  const float* Wo   = (const float*)d_in[6];
  const float* qg   = (const float*)d_in[7];

  char* w = (char*)d_ws;
  short* xb   = (short*)(w + 0);          //  8.0 MB  x bf16 [2048][2048]
  short* wqvb = (short*)(w + 8388608);    //  8.5 MB  [Wq;Wv] bf16 [2176][2048]
  short* wob  = (short*)(w + 17301504);   //  8.0 MB  Wo bf16
  short* vt   = (short*)(w + 25690112);   //  0.5 MB  V^T bf16 [128][2048]
  short* qb   = (short*)(w + 26214400);   //  8.0 MB  Q roped bf16 [16][2048][128]
  short* kb   = (short*)(w + 34603008);   //  8.0 MB  K roped bf16 [16][2048][128]
  short* attb = (short*)(w + 42991616);   //  8.0 MB  att bf16 [2048][2048]

  cast_f32_bf16<<<dim3(2048), dim3(256), 0, stream>>>(x,  xb,   4194304);
  cast_f32_bf16<<<dim3(2048), dim3(256), 0, stream>>>(Wq, wqvb, 4194304);
  cast_f32_bf16<<<dim3(128),  dim3(256), 0, stream>>>(Wv, wqvb + 4194304, 262144);
  cast_f32_bf16<<<dim3(2048), dim3(256), 0, stream>>>(Wo, wob,  4194304);

  gemm_fused<1><<<dim3(17, 16), dim3(256), 0, stream>>>(xb, wqvb, nullptr, qb, kb, vt,
                                                        cosT, sinT, qg);
  attn<<<dim3(32, 16), dim3(256), 0, stream>>>(qb, kb, vt, attb);
  gemm_fused<0><<<dim3(16, 16), dim3(256), 0, stream>>>(attb, wob, (float*)d_out,
                                                        nullptr, nullptr, nullptr,
                                                        nullptr, nullptr, nullptr);
}

// Round 7
// 158.089 us; speedup vs baseline: 1.9242x; 1.2652x over previous
//
#include <hip/hip_runtime.h>
#include <hip/hip_bf16.h>

#define SL 2048
#define NH 16
#define HD 128
#define EMB 2048

typedef __attribute__((ext_vector_type(8))) __bf16 bf16x8;
typedef __attribute__((ext_vector_type(4))) float f32x4;
typedef __attribute__((ext_vector_type(8))) short short8;

__device__ __forceinline__ short bf16bits(float x) {
  union { __hip_bfloat16 h; short s; } u;
  u.h = __float2bfloat16(x);
  return u.s;
}

#define GLDS16(gp, lp) __builtin_amdgcn_global_load_lds( \
    (__attribute__((address_space(1))) void*)(gp), \
    (__attribute__((address_space(3))) void*)(lp), 16, 0, 0)

// ---------------------------------------------------------------- casts
__global__ __launch_bounds__(256) void cast_f32_bf16(const float* __restrict__ in,
                                                     short* __restrict__ out, int n) {
  int i = (blockIdx.x * 256 + threadIdx.x) * 8;
  if (i >= n) return;
  float4 a = *(const float4*)(in + i);
  float4 b = *(const float4*)(in + i + 4);
  short8 o;
  o[0] = bf16bits(a.x); o[1] = bf16bits(a.y); o[2] = bf16bits(a.z); o[3] = bf16bits(a.w);
  o[4] = bf16bits(b.x); o[5] = bf16bits(b.y); o[6] = bf16bits(b.z); o[7] = bf16bits(b.w);
  *(short8*)(out + i) = o;
}

// --------------------------------- 2-phase dbuf NT GEMM, 64(M)x128(N) tile, 1D grid
// ~2 blocks/CU at this problem shape (vs 1 for 128x128) -> inter-block overlap.
// MODE 0: C f32 [2048][2048].  MODE 1: tn<16 fused rmsnorm+double-rope -> Qb,Kb;
// tn==16 -> VT bf16 [d][s] (what attn consumes).
// LDS arena: K-loop As(8KB)+Bs(16KB); MODE-1 epilogue reuses arena as xch (17.4KB).
template<int MODE>
__global__ __launch_bounds__(256, 3) void gemm64(const short* __restrict__ A,
                                                 const short* __restrict__ B,
                                                 float* __restrict__ C,
                                                 short* __restrict__ Qb,
                                                 short* __restrict__ Kb,
                                                 short* __restrict__ VT,
                                                 const float* __restrict__ cosT,
                                                 const float* __restrict__ sinT,
                                                 const float* __restrict__ gamma) {
  __shared__ char lds_raw[24576];
  short* As = (short*)lds_raw;             // [2][64*32]  8 KB
  short* Bs = (short*)(lds_raw + 8192);    // [2][128*32] 16 KB
  const int K = 2048;
  int nwg = gridDim.x;                          // multiple of 8
  int id = blockIdx.x;
  int nid = (id & 7) * (nwg >> 3) + (id >> 3);  // bijective XCD swizzle (nwg%8==0)
  int tn = nid >> 5;                            // consecutive nid share B panel
  int tm = nid & 31;
  int tid = threadIdx.x;
  int wave = tid >> 6, lane = tid & 63;
  int g = lane >> 4, c = lane & 15;
  int wr = wave >> 1, wc = wave & 1;
  const short* Ab = A + (long)(tm * 64) * K;
  const short* Bb = B + (long)(tn * 128) * K;
  f32x4 zero = {0.f, 0.f, 0.f, 0.f};
  f32x4 acc[2][4];
#pragma unroll
  for (int m = 0; m < 2; ++m)
#pragma unroll
    for (int n = 0; n < 4; ++n) acc[m][n] = zero;

#define STG(buf, kt) do { \
    GLDS16(Ab + (long)(wave * 16 + (lane >> 2)) * K + (kt) + (lane & 3) * 8, \
           As + (buf) * 2048 + wave * 512); \
    _Pragma("unroll") \
    for (int hh = 0; hh < 2; ++hh) { \
      int rb = wave * 32 + hh * 16; \
      GLDS16(Bb + (long)(rb + (lane >> 2)) * K + (kt) + (lane & 3) * 8, \
             Bs + (buf) * 4096 + rb * 32); \
    } } while (0)

  STG(0, 0);
  asm volatile("s_waitcnt vmcnt(0)" ::: "memory");
  __builtin_amdgcn_s_barrier();

  for (int it = 0; it < 64; ++it) {
    int cur = it & 1;
    if (it < 63) STG(cur ^ 1, (it + 1) * 32);
    bf16x8 a[2], b[4];
#pragma unroll
    for (int m = 0; m < 2; ++m)
      a[m] = *(const bf16x8*)(As + cur * 2048 + (wr * 32 + m * 16 + c) * 32 + g * 8);
#pragma unroll
    for (int n = 0; n < 4; ++n)
      b[n] = *(const bf16x8*)(Bs + cur * 4096 + (wc * 64 + n * 16 + c) * 32 + g * 8);
    __builtin_amdgcn_s_setprio(1);
#pragma unroll
    for (int m = 0; m < 2; ++m)
#pragma unroll
      for (int n = 0; n < 4; ++n)
        acc[m][n] = __builtin_amdgcn_mfma_f32_16x16x32_bf16(a[m], b[n], acc[m][n], 0, 0, 0);
    __builtin_amdgcn_s_setprio(0);
    if (it < 63) asm volatile("s_waitcnt vmcnt(0)" ::: "memory");
    __builtin_amdgcn_s_barrier();
  }
#undef STG

  if constexpr (MODE == 0) {
#pragma unroll
    for (int m = 0; m < 2; ++m)
#pragma unroll
      for (int n = 0; n < 4; ++n)
#pragma unroll
        for (int r = 0; r < 4; ++r) {
          int row = tm * 64 + wr * 32 + m * 16 + g * 4 + r;
          int col = tn * 128 + wc * 64 + n * 16 + c;
          C[(long)row * 2048 + col] = acc[m][n][r];
        }
  } else {
    if (tn < 16) {
      // fused rmsnorm + rope(Q) + rope(rope(Q))
      __shared__ float ssb[2][64];
      float* xch = (float*)lds_raw;   // 17.4 KB <= 24 KB arena (K-loop LDS dead)
      float ssmr[2][4];
#pragma unroll
      for (int m = 0; m < 2; ++m)
#pragma unroll
        for (int r = 0; r < 4; ++r) {
          float s = 0.f;
#pragma unroll
          for (int n = 0; n < 4; ++n) s += acc[m][n][r] * acc[m][n][r];
#pragma unroll
          for (int off = 1; off <= 8; off <<= 1) s += __shfl_xor(s, off, 64);
          ssmr[m][r] = s;
        }
      if (c == 0) {
#pragma unroll
        for (int m = 0; m < 2; ++m)
#pragma unroll
          for (int r = 0; r < 4; ++r)
            ssb[wc][wr * 32 + m * 16 + g * 4 + r] = ssmr[m][r];
      }
      __syncthreads();
      float rn[2][4];
#pragma unroll
      for (int m = 0; m < 2; ++m)
#pragma unroll
        for (int r = 0; r < 4; ++r) {
          int rowloc = wr * 32 + m * 16 + g * 4 + r;
          rn[m][r] = rsqrtf((ssb[0][rowloc] + ssb[1][rowloc]) * (1.0f / 128.0f) + 1e-6f);
        }
      float g_own[4], g_par[4];
#pragma unroll
      for (int n = 0; n < 4; ++n) {
        g_own[n] = gamma[wc * 64 + n * 16 + c];
        g_par[n] = gamma[(wc ^ 1) * 64 + n * 16 + c];
      }
      float sgn = wc ? 1.f : -1.f;
#pragma unroll
      for (int m = 0; m < 2; ++m) {
        __syncthreads();   // waves done with K-loop LDS / previous xch use (WAR)
#pragma unroll
        for (int n = 0; n < 4; ++n)
#pragma unroll
          for (int r = 0; r < 4; ++r)
            xch[tid * 17 + n * 4 + r] = acc[m][n][r];
        __syncthreads();
        float xp[4][4];
#pragma unroll
        for (int n = 0; n < 4; ++n)
#pragma unroll
          for (int r = 0; r < 4; ++r)
            xp[n][r] = xch[(tid ^ 64) * 17 + n * 4 + r];
#pragma unroll
        for (int n = 0; n < 4; ++n)
#pragma unroll
          for (int r = 0; r < 4; ++r) {
            int s = tm * 64 + wr * 32 + m * 16 + g * 4 + r;
            int u = n * 16 + c;                    // cos/sin periodic in 64
            float cv = cosT[s * 128 + u];
            float sv = sinT[s * 128 + u];
            float xo = acc[m][n][r] * rn[m][r] * g_own[n];
            float xq = xp[n][r] * rn[m][r] * g_par[n];
            float y  = xo * cv + sgn * xq * sv;    // rope(Q)
            float yp = xq * cv - sgn * xo * sv;    // rope(Q) at partner d
            float kk = y * cv + sgn * yp * sv;     // rope(rope(Q))  (source bug)
            long o = ((long)tn * SL + s) * HD + wc * 64 + u;
            Qb[o] = bf16bits(y);
            Kb[o] = bf16bits(kk);
          }
      }
    } else {
      // V^T [d][s]  (what attn consumes)
#pragma unroll
      for (int m = 0; m < 2; ++m)
#pragma unroll
        for (int n = 0; n < 4; ++n)
#pragma unroll
          for (int r = 0; r < 4; ++r) {
            int s = tm * 64 + wr * 32 + m * 16 + g * 4 + r;
            int d = wc * 64 + n * 16 + c;
            VT[(long)d * SL + s] = bf16bits(acc[m][n][r]);
          }
    }
  }
}

// ---------------------------------------------------------- causal flash attention
// (r6-proven, verbatim) grid (32,16): 64 q rows/block, 4 waves x 16 rows; KV tiles
// 64; qt pairing.  K tile: GLDS dbuf, source chunk-swizzle (c ^ (row&7)).
// V tile: V^T [128d][64k] staged by GLDS with the SAME swizzle; B-frags plain bf16x8
// LDS reads.  ONE barrier/iter; defer-max (T13); row-sum reduce in epilogue.
__global__ __launch_bounds__(256, 2) void attn(const short* __restrict__ Qb,
                                               const short* __restrict__ Kb,
                                               const short* __restrict__ VTg,
                                               short* __restrict__ att) {
  __shared__ short Ks[2][64 * 128];   // 32 KB
  __shared__ short Vs[2][128 * 64];   // 32 KB  V^T tile [d][k-chunk swizzled]
  __shared__ short Ps[4][16 * 72];    // 9 KB per-wave
  int wave = threadIdx.x >> 6, lane = threadIdx.x & 63;
  int g = lane >> 4, c = lane & 15;
  int h = blockIdx.y;
  int qt = (blockIdx.y & 8) ? (31 - blockIdx.x) : blockIdx.x;
  int qbase = qt * 64 + wave * 16;
  int ntile = qt + 1;
  const short* Qh = Qb + (long)h * SL * HD;
  const short* Kh = Kb + (long)h * SL * HD;

  bf16x8 aq[4];
#pragma unroll
  for (int kc = 0; kc < 4; ++kc)
    aq[kc] = *(const bf16x8*)(Qh + (long)(qbase + c) * HD + kc * 32 + g * 8);

  float mrun[4], lrun[4];
#pragma unroll
  for (int r = 0; r < 4; ++r) { mrun[r] = -1e30f; lrun[r] = 0.f; }
  f32x4 zero = {0.f, 0.f, 0.f, 0.f};
  f32x4 O[8];
#pragma unroll
  for (int d8 = 0; d8 < 8; ++d8) O[d8] = zero;

#define ASTAGE(b, kvb) do { \
    _Pragma("unroll") \
    for (int i = 0; i < 4; ++i) { \
      int rb = wave * 16 + i * 4; \
      int row = rb + (lane >> 4); \
      int c16 = (lane & 15) ^ (row & 7); \
      GLDS16(Kh + (long)((kvb) + row) * HD + c16 * 8, &Ks[b][rb * 128]); \
    } \
    _Pragma("unroll") \
    for (int i = 0; i < 4; ++i) { \
      int dbase = i * 32 + wave * 8; \
      int drow = dbase + (lane >> 3); \
      int u8 = (lane & 7) ^ (drow & 7); \
      GLDS16(VTg + (long)drow * SL + (kvb) + u8 * 8, &Vs[b][dbase * 64]); \
    } } while (0)

  ASTAGE(0, 0);

  for (int kt = 0; kt < ntile; ++kt) {
    int kvb = kt * 64;
    int bcu = kt & 1;
    asm volatile("s_waitcnt vmcnt(0)" ::: "memory");
    __builtin_amdgcn_s_barrier();
    if (kt + 1 < ntile) ASTAGE(bcu ^ 1, kvb + 64);

    // S = Q K^T
    f32x4 sf[4];
#pragma unroll
    for (int n = 0; n < 4; ++n) sf[n] = zero;
    __builtin_amdgcn_s_setprio(1);
#pragma unroll
    for (int kc = 0; kc < 4; ++kc)
#pragma unroll
      for (int n = 0; n < 4; ++n) {
        int row = n * 16 + c;
        int u = (kc * 4 + g) ^ (row & 7);
        bf16x8 bk = *(const bf16x8*)(&Ks[bcu][row * 128 + u * 8]);
        sf[n] = __builtin_amdgcn_mfma_f32_16x16x32_bf16(aq[kc], bk, sf[n], 0, 0, 0);
      }
    __builtin_amdgcn_s_setprio(0);

    const float sc = 0.08838834764831845f;   // 1/sqrt(128)
    float tmax[4];
#pragma unroll
    for (int r = 0; r < 4; ++r) tmax[r] = -1e30f;
#pragma unroll
    for (int n = 0; n < 4; ++n)
#pragma unroll
      for (int r = 0; r < 4; ++r) {
        int q = qbase + g * 4 + r;
        int k = kvb + n * 16 + c;
        float v = sf[n][r] * sc;
        if (k > q) v = -1e30f;
        sf[n][r] = v;
        tmax[r] = fmaxf(tmax[r], v);
      }
#pragma unroll
    for (int r = 0; r < 4; ++r) {
      tmax[r] = fmaxf(tmax[r], __shfl_xor(tmax[r], 1, 64));
      tmax[r] = fmaxf(tmax[r], __shfl_xor(tmax[r], 2, 64));
      tmax[r] = fmaxf(tmax[r], __shfl_xor(tmax[r], 4, 64));
      tmax[r] = fmaxf(tmax[r], __shfl_xor(tmax[r], 8, 64));
    }
    int need = 0;
#pragma unroll
    for (int r = 0; r < 4; ++r) need |= (tmax[r] > mrun[r] + 8.f);
    if (__any(need)) {
#pragma unroll
      for (int r = 0; r < 4; ++r) {
        float mn = fmaxf(mrun[r], tmax[r]);
        float corr = __expf(mrun[r] - mn);
        mrun[r] = mn;
        lrun[r] *= corr;
#pragma unroll
        for (int d8 = 0; d8 < 8; ++d8) O[d8][r] *= corr;
      }
    }
    float rs[4] = {0.f, 0.f, 0.f, 0.f};
#pragma unroll
    for (int n = 0; n < 4; ++n)
#pragma unroll
      for (int r = 0; r < 4; ++r) {
        float p = __expf(sf[n][r] - mrun[r]);
        rs[r] += p;
        Ps[wave][(g * 4 + r) * 72 + n * 16 + c] = bf16bits(p);
      }
#pragma unroll
    for (int r = 0; r < 4; ++r) lrun[r] += rs[r];

    // O += P V
#pragma unroll
    for (int k2 = 0; k2 < 2; ++k2) {
      bf16x8 ap = *(const bf16x8*)(&Ps[wave][c * 72 + k2 * 32 + g * 8]);
      __builtin_amdgcn_s_setprio(1);
#pragma unroll
      for (int d8 = 0; d8 < 8; ++d8) {
        int drow = d8 * 16 + c;
        int u = (k2 * 4 + g) ^ (c & 7);
        bf16x8 bv = *(const bf16x8*)(&Vs[bcu][drow * 64 + u * 8]);
        O[d8] = __builtin_amdgcn_mfma_f32_16x16x32_bf16(ap, bv, O[d8], 0, 0, 0);
      }
      __builtin_amdgcn_s_setprio(0);
    }
  }
#undef ASTAGE

  float rsum[4];
#pragma unroll
  for (int r = 0; r < 4; ++r) {
    float s = lrun[r];
    s += __shfl_xor(s, 1, 64);
    s += __shfl_xor(s, 2, 64);
    s += __shfl_xor(s, 4, 64);
    s += __shfl_xor(s, 8, 64);
    rsum[r] = 1.0f / s;
  }
#pragma unroll
  for (int d8 = 0; d8 < 8; ++d8)
#pragma unroll
    for (int r = 0; r < 4; ++r) {
      int q = qbase + g * 4 + r;
      att[(long)q * EMB + h * HD + d8 * 16 + c] = bf16bits(O[d8][r] * rsum[r]);
    }
}

// ---------------------------------------------------------------------- launch
extern "C" void kernel_launch(void* const* d_in, const int* in_sizes, int n_in,
                              void* d_out, int out_size, void* d_ws, size_t ws_size,
                              hipStream_t stream) {
  const float* x    = (const float*)d_in[0];
  const float* cosT = (const float*)d_in[1];
  const float* sinT = (const float*)d_in[2];
  const float* Wq   = (const float*)d_in[3];
  const float* Wv   = (const float*)d_in[5];
  const float* Wo   = (const float*)d_in[6];
  const float* qg   = (const float*)d_in[7];

  char* w = (char*)d_ws;
  short* xb   = (short*)(w + 0);          //  8.0 MB  x bf16 [2048][2048]
  short* wqvb = (short*)(w + 8388608);    //  8.5 MB  [Wq;Wv] bf16 [2176][2048]
  short* wob  = (short*)(w + 17301504);   //  8.0 MB  Wo bf16
  short* vt   = (short*)(w + 25690112);   //  0.5 MB  V^T bf16 [128][2048]
  short* qb   = (short*)(w + 26214400);   //  8.0 MB  Q roped bf16 [16][2048][128]
  short* kb   = (short*)(w + 34603008);   //  8.0 MB  K roped bf16 [16][2048][128]
  short* attb = (short*)(w + 42991616);   //  8.0 MB  att bf16 [2048][2048]

  cast_f32_bf16<<<dim3(2048), dim3(256), 0, stream>>>(x,  xb,   4194304);
  cast_f32_bf16<<<dim3(2048), dim3(256), 0, stream>>>(Wq, wqvb, 4194304);
  cast_f32_bf16<<<dim3(128),  dim3(256), 0, stream>>>(Wv, wqvb + 4194304, 262144);
  cast_f32_bf16<<<dim3(2048), dim3(256), 0, stream>>>(Wo, wob,  4194304);

  gemm64<1><<<dim3(544), dim3(256), 0, stream>>>(xb, wqvb, nullptr, qb, kb, vt,
                                                 cosT, sinT, qg);
  attn<<<dim3(32, 16), dim3(256), 0, stream>>>(qb, kb, vt, attb);
  gemm64<0><<<dim3(512), dim3(256), 0, stream>>>(attb, wob, (float*)d_out,
                                                 nullptr, nullptr, nullptr,
                                                 nullptr, nullptr, nullptr);
}